// Round 16
// baseline (277.009 us; speedup 1.0000x reference)
//
#include <hip/hip_runtime.h>

// ---------------- types / helpers ----------------
typedef __attribute__((ext_vector_type(8))) __bf16 bf16x8;
typedef __attribute__((ext_vector_type(4))) float  f32x4;

#define GPTR(p)   (__attribute__((address_space(1))) void*)(p)
#define LDSPTR(p) (__attribute__((address_space(3))) void*)(p)
#define MFMA16 __builtin_amdgcn_mfma_f32_16x16x32_bf16
#define SB() __builtin_amdgcn_sched_barrier(0)

__device__ __forceinline__ unsigned short f2bf(float f) {
    union { float f; unsigned u; } v; v.f = f;
    unsigned r = v.u + 0x7FFF + ((v.u >> 16) & 1);   // RNE
    return (unsigned short)(r >> 16);
}

// Problem constants
#define MTOT   30400
#define MPAD   30464
#define KTOT   4608
#define NT     72          // K tiles of 64

// ---------------- 1) fused prep_all: Wt (B^T), head W2/b2, P border zero, pad_transpose ----
__global__ __launch_bounds__(256) void prep_all(
    const float* __restrict__ cw,
    const float* __restrict__ cls_w, const float* __restrict__ reg_w,
    const float* __restrict__ cls_b, const float* __restrict__ reg_b,
    const float* __restrict__ fm,
    unsigned short* __restrict__ Wt,
    unsigned short* __restrict__ W2, float* __restrict__ b2,
    unsigned short* __restrict__ P)
{
    __shared__ float t[32][65];
    int bid = blockIdx.x;
    if (bid < 9216) {                               // Wt
        int i = bid * 256 + threadIdx.x;            // < 512*4608
        int o = i / KTOT;
        int r = i - o * KTOT;
        int kk = r >> 9;
        int c  = r & 511;
        Wt[i] = f2bf(cw[(o * 512 + c) * 9 + kk]);
    } else if (bid < 9344) {                        // W2[64][512], b2[64]
        int i = (bid - 9216) * 256 + threadIdx.x;   // < 64*512
        int n = i >> 9, k = i & 511;
        float v = 0.f;
        if (n < 18) v = cls_w[n * 512 + k];
        else if (n < 54) v = reg_w[(n - 18) * 512 + k];
        W2[i] = f2bf(v);
        if (i < 64) {
            float bv = 0.f;
            if (i < 18) bv = cls_b[i];
            else if (i < 54) bv = reg_b[i - 18];
            b2[i] = bv;
        }
    } else if (bid < 9856) {                        // P pad-border zero
        int i = (bid - 9344) * 256 + threadIdx.x;   // < 8*256*64 = 131072
        int b   = i >> 14;
        int rem = i & 16383;
        int seg = rem >> 6;                         // 0..255
        int c8  = (rem & 63) << 3;
        int y, x;
        if (seg < 78)       { y = 0;  x = seg; }
        else if (seg < 156) { y = 51; x = seg - 78; }
        else if (seg < 206) { y = seg - 155; x = 0; }
        else                { y = seg - 205; x = 77; }
        *(float4*)(P + ((b * 52 + y) * 78 + x) * 512 + c8) = make_float4(0.f, 0.f, 0.f, 0.f);
    } else {                                        // pad_transpose interior
        int bid2 = bid - 9856;                      // < 24*50*8 = 9600
        const int tid = threadIdx.x;
        const int tx  = tid & 31;                   // x within tile (read side)
        const int ty  = tid >> 5;                   // 0..7
        const int xp  = bid2 % 24;
        const int tix = xp % 3;                     // x tile (0..2)
        const int cix = xp / 3;                     // c tile (0..7)
        const int y   = (bid2 / 24) % 50;
        const int b   = bid2 / 1200;
        const int x0  = tix * 32, c0 = cix * 64;

        const int x = x0 + tx;
        if (x < 76) {
#pragma unroll
            for (int i = 0; i < 8; ++i) {
                int cc = i * 8 + ty;                // 0..63
                t[tx][cc] = fm[((b * 512 + c0 + cc) * 50 + y) * 76 + x];
            }
        }
        __syncthreads();

        const int p = tid >> 6;                     // pixel group 0..3
        const int c = tid & 63;                     // channel lane
#pragma unroll
        for (int xi = 0; xi < 8; ++xi) {
            int xr = p * 8 + xi;                    // 0..31
            int xw = x0 + xr;
            if (xw < 76)
                P[((b * 52 + y + 1) * 78 + (xw + 1)) * 512 + c0 + c] = f2bf(t[xr][c]);
        }
    }
}

// ---------------- 4) conv implicit GEMM: A via LDS, B DIRECT from global (L2/L3) ----------
// 256x256, BK=64, 8 waves (2M x 4N), 1 sync/tile double buffer (A only, 64KB),
// st_16x32 swizzle on A via pre-swizzled global source, XCD-chunked grid.
//
// Corrected cycle model of r12/r15 (143.5us, 4770 cyc/tile): MFMA = 512/4SIMD
// x 4.85 = 620 cyc; LDS reads 192 x b128 x 12 = 2300 cyc (shared per-CU pipe);
// staging writes ~500. LDS-READ-PIPE-bound, not MFMA-bound. Fix: Wt is 4.7MB,
// L2/L3-resident, and a lane's B fragment is 16B CONTIGUOUS in Wt
// (row*4608 + g*64 + ks*32 + (l>>4)*8; row = n0+nc*64+ni*16+(l&15) — identical
// element mapping to the old LDS path since nc*64+ni*16 = hB*128+(rB+ni)*16).
// So B loads straight to registers: LDS reads/tile 192->128, staging 32->16
// instr, LDS 128->64KB. Both-ks B issued at tile top so L2 latency hides
// under A reads + ks0 MFMAs. New pipe floor ~1800 cyc/tile.
__global__ __launch_bounds__(512, 2) void conv_gemm8(
    const unsigned short* __restrict__ P,    // padded NHWC bf16
    const unsigned short* __restrict__ Wt,   // [512][4608] bf16
    const float* __restrict__ bias,
    unsigned short* __restrict__ F)          // [MPAD][512] bf16
{
    __shared__ __attribute__((aligned(1024))) unsigned char lds[65536];   // A only

    const int tid = threadIdx.x;
    const int l   = tid & 63;
    const int w   = tid >> 6;          // wave 0..7
    const int wr  = w >> 2;            // M group 0..1 (owns 128 rows = one A half)
    const int nc  = w & 3;             // N group 0..3 (owns 64 cols)

    // bijective XCD-chunked block swizzle (nwg=238=8*29+6, m204 formula)
    const int orig = blockIdx.y * 119 + blockIdx.x;
    const int xcd = orig & 7, seq = orig >> 3;
    const int wg  = (xcd < 6 ? xcd * 30 : 180 + (xcd - 6) * 29) + seq;
    const int m0  = (wg % 119) * 256;
    const int n0  = (wg / 119) * 256;

    // swizzled read lane offset within a 1024B subtile (A)
    const int loff = (l & 15) * 64 + (((l >> 4) * 16) ^ ((l & 8) ? 32 : 0));
    // swizzled stage source k-element offset (inverse of read swizzle)
    const int kelS = ((l & 3) * 8) ^ ((l & 32) ? 16 : 0);

    // Per-thread global base offsets for A staging (half h, load j).
    int cbA[2][2];
#pragma unroll
    for (int h = 0; h < 2; ++h)
#pragma unroll
        for (int j = 0; j < 2; ++j) {
            const int s    = j * 8 + w;                          // subtile 0..15
            const int rowt = h * 128 + (s >> 1) * 16 + (l >> 2); // row in 256-tile
            int m = m0 + rowt; if (m >= MTOT) m = 0;             // clamp (stores guarded)
            int b = m / 3800; int r = m - b * 3800;
            int y = r / 76;   int x = r - y * 76;
            cbA[h][j] = ((b * 52 + y + 1) * 78 + (x + 1)) * 512 + (s & 1) * 32 + kelS;
        }

    // Per-lane B fragment bases (direct global): row*KTOT + (l>>4)*8
    int bB[4];
#pragma unroll
    for (int ni = 0; ni < 4; ++ni)
        bB[ni] = (n0 + nc * 64 + ni * 16 + (l & 15)) * KTOT + ((l >> 4) * 8);

    auto stA = [&](int t, int h, unsigned char* abase) {
        const int kk  = t >> 3;
        const int tap = ((kk / 3 - 1) * 78 + (kk % 3 - 1)) * 512 + (t & 7) * 64;
#pragma unroll
        for (int j = 0; j < 2; ++j)
            __builtin_amdgcn_global_load_lds(GPTR(P + cbA[h][j] + tap),
                LDSPTR(abase + h * 16384 + j * 8192 + w * 1024), 16, 0, 0);
    };

    f32x4 acc[8][4];
#pragma unroll
    for (int i = 0; i < 8; ++i)
#pragma unroll
        for (int j = 0; j < 4; ++j) acc[i][j] = (f32x4){0.f, 0.f, 0.f, 0.f};

#define RD(basep, subR, ks) (*(const bf16x8*)((basep) + (((subR) * 2 + (ks)) * 1024) + loff))

    // ---- prologue: stage A tile 0 into buf0; single sync ----
    stA(0, 0, lds); stA(0, 1, lds);
    __syncthreads();

    for (int g = 0; g < NT; ++g) {
        unsigned char* Ac = lds + (g & 1) * 32768;
        unsigned char* An = lds + (((g & 1) ^ 1)) * 32768;
        unsigned char* Ah = Ac + wr * 16384;   // this wave's A half

        // stage A tile g+1 into the idle buffer (full-tile latency cover)
        if (g + 1 < NT) { stA(g + 1, 0, An); stA(g + 1, 1, An); }

        // issue B loads for both k-halves (L2/L3-resident Wt, 16B contiguous/lane)
        bf16x8 b0[4], b1[4];
#pragma unroll
        for (int ni = 0; ni < 4; ++ni) {
            b0[ni] = *(const bf16x8*)(Wt + bB[ni] + g * 64);
            b1[ni] = *(const bf16x8*)(Wt + bB[ni] + g * 64 + 32);
        }
        SB();

        // k-half-major: {8 A reads, 32 MFMA} x 2; B already in flight/registers
#pragma unroll
        for (int ks = 0; ks < 2; ++ks) {
            bf16x8 a[8];
#pragma unroll
            for (int f = 0; f < 8; ++f) a[f] = RD(Ah, f, ks);
#pragma unroll
            for (int n = 0; n < 4; ++n)
#pragma unroll
                for (int f = 0; f < 8; ++f)
                    acc[f][n] = MFMA16(a[f], (ks ? b1 : b0)[n], acc[f][n], 0, 0, 0);
        }

        // single per-tile sync: drains A-staging (and B) loads, publishes next buf
        __syncthreads();
    }
#undef RD

    // ---- epilogue: bias + relu + bf16 store ----
#pragma unroll
    for (int ni = 0; ni < 4; ++ni) {
        const int col = n0 + nc * 64 + ni * 16 + (l & 15);
        const float bcol = bias[col];
#pragma unroll
        for (int mi = 0; mi < 8; ++mi) {
#pragma unroll
            for (int jj = 0; jj < 4; ++jj) {
                const int row = m0 + wr * 128 + mi * 16 + (l >> 4) * 4 + jj;
                if (row < MTOT)
                    F[row * 512 + col] = f2bf(fmaxf(acc[mi][ni][jj] + bcol, 0.f));
            }
        }
    }
}

// ---------------- 5) head GEMM (N=54 in 64) + anchor decode ----------------
__global__ __launch_bounds__(256) void head_decode(
    const unsigned short* __restrict__ F,
    const unsigned short* __restrict__ W2,
    const float* __restrict__ b2,
    const int* __restrict__ img,
    float* __restrict__ out)
{
    __shared__ float S[64][56];
    const int tid  = threadIdx.x;
    const int lane = tid & 63;
    const int wv   = tid >> 6;
    const int mblk = blockIdx.x * 64;
    int arow = mblk + wv * 16 + (lane & 15);
    if (arow >= MTOT) arow = MTOT - 1;   // clamp: tail S rows computed but never decoded

    f32x4 acc[4];
#pragma unroll
    for (int ni = 0; ni < 4; ++ni) acc[ni] = (f32x4){0.f, 0.f, 0.f, 0.f};

#pragma unroll 4
    for (int ks = 0; ks < 16; ++ks) {
        const int kloc = ks * 32 + (lane >> 4) * 8;
        bf16x8 a = *(const bf16x8*)(F + arow * 512 + kloc);
#pragma unroll
        for (int ni = 0; ni < 4; ++ni) {
            bf16x8 b = *(const bf16x8*)(W2 + (ni * 16 + (lane & 15)) * 512 + kloc);
            acc[ni] = MFMA16(a, b, acc[ni], 0, 0, 0);
        }
    }

#pragma unroll
    for (int ni = 0; ni < 4; ++ni) {
        int col = ni * 16 + (lane & 15);
        if (col < 54) {
            float bb = b2[col];
#pragma unroll
            for (int j = 0; j < 4; ++j)
                S[wv * 16 + (lane >> 4) * 4 + j][col] = acc[ni][j] + bb;
        }
    }
    __syncthreads();

    for (int it = tid; it < 576; it += 256) {
        int rowl = it / 9;
        int a    = it - rowl * 9;
        int m = mblk + rowl;
        if (m >= MTOT) continue;
        int b   = m / 3800;
        int rem = m - b * 3800;
        int y = rem / 76;
        int x = rem - y * 76;

        int ri = a / 3, si = a - ri * 3;
        float sqr = (ri == 0) ? 0.70710678118654752f : ((ri == 1) ? 1.f : 1.41421356237309515f);
        float scale = (float)(128 << si);
        float wa = scale / sqr;
        float ha = scale * sqr;
        float ax = (float)x * 16.f + 8.f;
        float ay = (float)y * 16.f + 8.f;

        float r0 = S[rowl][18 + a * 4 + 0];
        float r1 = S[rowl][18 + a * 4 + 1];
        float r2 = S[rowl][18 + a * 4 + 2];
        float r3 = S[rowl][18 + a * 4 + 3];

        float px = ax + r0 * wa;
        float py = ay + r1 * ha;
        float pw = wa * expf(r2);
        float ph = ha * expf(r3);

        float x1 = px - 0.5f * pw, y1 = py - 0.5f * ph;
        float x2 = x1 + pw,        y2 = y1 + ph;
        float imx = (float)img[2 * b], imy = (float)img[2 * b + 1];
        x1 = fminf(fmaxf(x1, 0.f), imx); x2 = fminf(fmaxf(x2, 0.f), imx);
        y1 = fminf(fmaxf(y1, 0.f), imy); y2 = fminf(fmaxf(y2, 0.f), imy);
        float ww = x2 - x1, hh = y2 - y1;
        float cx = x1 + 0.5f * ww, cy = y1 + 0.5f * hh;

        int pidx = b * 34200 + rem * 9 + a;
        ((float4*)out)[pidx] = make_float4(cx, cy, ww, hh);
        float* oc = out + 1094400 + pidx * 2;
        oc[0] = S[rowl][a * 2 + 0];
        oc[1] = S[rowl][a * 2 + 1];
    }
}

// ---------------- launcher ----------------
extern "C" void kernel_launch(void* const* d_in, const int* in_sizes, int n_in,
                              void* d_out, int out_size, void* d_ws, size_t ws_size,
                              hipStream_t stream) {
    const float* fm     = (const float*)d_in[0];
    const float* conv_w = (const float*)d_in[1];
    const float* conv_b = (const float*)d_in[2];
    const float* cls_w  = (const float*)d_in[3];
    const float* cls_b  = (const float*)d_in[4];
    const float* reg_w  = (const float*)d_in[5];
    const float* reg_b  = (const float*)d_in[6];
    const int*   img    = (const int*)d_in[7];
    float* out = (float*)d_out;

    char* ws = (char*)d_ws;
    unsigned short* P  = (unsigned short*)(ws);
    unsigned short* Wt = (unsigned short*)(ws + 33226752);
    unsigned short* F  = (unsigned short*)(ws + 37945344);
    unsigned short* W2 = (unsigned short*)(ws + 69140480);
    float*          b2 = (float*)(ws + 69206016);

    // prep_all: Wt (9216) + head weights (128) + P border zero (512) + pad_transpose (9600)
    prep_all<<<19456, 256, 0, stream>>>(conv_w, cls_w, reg_w, cls_b, reg_b, fm,
                                        Wt, W2, b2, P);
    conv_gemm8<<<dim3(119, 2), 512, 0, stream>>>(P, Wt, conv_b, F);
    head_decode<<<475, 256, 0, stream>>>(F, W2, b2, img, out);
}

// Round 17
// 192.505 us; speedup vs baseline: 1.4390x; 1.4390x over previous
//
#include <hip/hip_runtime.h>

// ---------------- types / helpers ----------------
typedef __attribute__((ext_vector_type(8))) __bf16 bf16x8;
typedef __attribute__((ext_vector_type(4))) float  f32x4;

#define GPTR(p)   (__attribute__((address_space(1))) void*)(p)
#define LDSPTR(p) (__attribute__((address_space(3))) void*)(p)
#define MFMA16 __builtin_amdgcn_mfma_f32_16x16x32_bf16
#define SB() __builtin_amdgcn_sched_barrier(0)

__device__ __forceinline__ unsigned short f2bf(float f) {
    union { float f; unsigned u; } v; v.f = f;
    unsigned r = v.u + 0x7FFF + ((v.u >> 16) & 1);   // RNE
    return (unsigned short)(r >> 16);
}

// Problem constants
#define MTOT   30400
#define MPAD   30464
#define KTOT   4608
#define NT     72          // K tiles of 64

// ---------------- 1) fused prep_all: Wt (B^T), head W2/b2, P border zero, pad_transpose ----
__global__ __launch_bounds__(256) void prep_all(
    const float* __restrict__ cw,
    const float* __restrict__ cls_w, const float* __restrict__ reg_w,
    const float* __restrict__ cls_b, const float* __restrict__ reg_b,
    const float* __restrict__ fm,
    unsigned short* __restrict__ Wt,
    unsigned short* __restrict__ W2, float* __restrict__ b2,
    unsigned short* __restrict__ P)
{
    __shared__ float t[32][65];
    int bid = blockIdx.x;
    if (bid < 9216) {                               // Wt
        int i = bid * 256 + threadIdx.x;            // < 512*4608
        int o = i / KTOT;
        int r = i - o * KTOT;
        int kk = r >> 9;
        int c  = r & 511;
        Wt[i] = f2bf(cw[(o * 512 + c) * 9 + kk]);
    } else if (bid < 9344) {                        // W2[64][512], b2[64]
        int i = (bid - 9216) * 256 + threadIdx.x;   // < 64*512
        int n = i >> 9, k = i & 511;
        float v = 0.f;
        if (n < 18) v = cls_w[n * 512 + k];
        else if (n < 54) v = reg_w[(n - 18) * 512 + k];
        W2[i] = f2bf(v);
        if (i < 64) {
            float bv = 0.f;
            if (i < 18) bv = cls_b[i];
            else if (i < 54) bv = reg_b[i - 18];
            b2[i] = bv;
        }
    } else if (bid < 9856) {                        // P pad-border zero
        int i = (bid - 9344) * 256 + threadIdx.x;   // < 8*256*64 = 131072
        int b   = i >> 14;
        int rem = i & 16383;
        int seg = rem >> 6;                         // 0..255
        int c8  = (rem & 63) << 3;
        int y, x;
        if (seg < 78)       { y = 0;  x = seg; }
        else if (seg < 156) { y = 51; x = seg - 78; }
        else if (seg < 206) { y = seg - 155; x = 0; }
        else                { y = seg - 205; x = 77; }
        *(float4*)(P + ((b * 52 + y) * 78 + x) * 512 + c8) = make_float4(0.f, 0.f, 0.f, 0.f);
    } else {                                        // pad_transpose interior
        int bid2 = bid - 9856;                      // < 24*50*8 = 9600
        const int tid = threadIdx.x;
        const int tx  = tid & 31;                   // x within tile (read side)
        const int ty  = tid >> 5;                   // 0..7
        const int xp  = bid2 % 24;
        const int tix = xp % 3;                     // x tile (0..2)
        const int cix = xp / 3;                     // c tile (0..7)
        const int y   = (bid2 / 24) % 50;
        const int b   = bid2 / 1200;
        const int x0  = tix * 32, c0 = cix * 64;

        const int x = x0 + tx;
        if (x < 76) {
#pragma unroll
            for (int i = 0; i < 8; ++i) {
                int cc = i * 8 + ty;                // 0..63
                t[tx][cc] = fm[((b * 512 + c0 + cc) * 50 + y) * 76 + x];
            }
        }
        __syncthreads();

        const int p = tid >> 6;                     // pixel group 0..3
        const int c = tid & 63;                     // channel lane
#pragma unroll
        for (int xi = 0; xi < 8; ++xi) {
            int xr = p * 8 + xi;                    // 0..31
            int xw = x0 + xr;
            if (xw < 76)
                P[((b * 52 + y + 1) * 78 + (xw + 1)) * 512 + c0 + c] = f2bf(t[xr][c]);
        }
    }
}

// ---------------- 4) conv implicit GEMM: counted-vmcnt, A 3-buf / B 2-buf (160KB) ----------
// 256x256, BK=64, 8 waves (2M x 4N), k-half-major body (r15 verbatim compute),
// st_16x32 swizzle via pre-swizzled global source, XCD-chunked grid.
//
// NEW vs r15 (143.5us): replace __syncthreads (full vmcnt(0)+lgkm drain) with
// raw s_barrier + COUNTED vmcnt, enabled by A prefetch depth 2 (3 buffers)
// while B stays depth 1 (2 buffers). LDS = 3*32KB (A) + 2*32KB (B) = 160KB.
// FIFO ledger (stA/stB = 4 loads each; B ISSUED BEFORE A so B(g+1) is older):
//   steady iter g end: outstanding [A(g+1)x4, B(g+1)x4, A(g+2)x4] = 12
//   -> vmcnt(4) retires A(g+1)+B(g+1) (published for next iter), A(g+2) stays
//   in flight ACROSS the barrier (never drain to 0 mid-loop).
//   Prologue: B0,A0,A1 issued (12) -> vmcnt(4) retires B0+A0.
//   Tail g=70: only stB(71) -> [A71x4,B71x4]=8 -> vmcnt(0). g=71: none.
// Race audit: every buffer overwritten is >=1 barrier after its last ds_read
// (reads retire before their consuming MFMAs, which precede the barrier).
__global__ __launch_bounds__(512, 2) void conv_gemm8(
    const unsigned short* __restrict__ P,    // padded NHWC bf16
    const unsigned short* __restrict__ Wt,   // [512][4608] bf16
    const float* __restrict__ bias,
    unsigned short* __restrict__ F)          // [MPAD][512] bf16
{
    __shared__ __attribute__((aligned(1024))) unsigned char lds[163840];

    const int tid = threadIdx.x;
    const int l   = tid & 63;
    const int w   = tid >> 6;          // wave 0..7
    const int wr  = w >> 2;            // M group 0..1 (owns 128 rows = one A half)
    const int nc  = w & 3;             // N group 0..3 (owns 64 cols)
    const int hB  = nc >> 1;           // which B half this wave reads
    const int rB  = (nc & 1) * 4;      // subtile-R base within the B half

    // bijective XCD-chunked block swizzle (nwg=238=8*29+6, m204 formula)
    const int orig = blockIdx.y * 119 + blockIdx.x;
    const int xcd = orig & 7, seq = orig >> 3;
    const int wg  = (xcd < 6 ? xcd * 30 : 180 + (xcd - 6) * 29) + seq;
    const int m0  = (wg % 119) * 256;
    const int n0  = (wg / 119) * 256;

    // swizzled read lane offset within a 1024B subtile
    const int loff = (l & 15) * 64 + (((l >> 4) * 16) ^ ((l & 8) ? 32 : 0));
    // swizzled stage source k-element offset (inverse of read swizzle)
    const int kelS = ((l & 3) * 8) ^ ((l & 32) ? 16 : 0);

    // Per-thread global base offsets for staging (half h, load j).
    int cbA[2][2], nbB[2][2];
#pragma unroll
    for (int h = 0; h < 2; ++h)
#pragma unroll
        for (int j = 0; j < 2; ++j) {
            const int s    = j * 8 + w;                          // subtile 0..15
            const int rowt = h * 128 + (s >> 1) * 16 + (l >> 2); // row in 256-tile
            int m = m0 + rowt; if (m >= MTOT) m = 0;             // clamp (stores guarded)
            int b = m / 3800; int r = m - b * 3800;
            int y = r / 76;   int x = r - y * 76;
            cbA[h][j] = ((b * 52 + y + 1) * 78 + (x + 1)) * 512 + (s & 1) * 32 + kelS;
            nbB[h][j] = (n0 + rowt) * KTOT + (s & 1) * 32 + kelS;
        }

    auto stA = [&](int t, unsigned char* abase) {
        const int kk  = t >> 3;
        const int tap = ((kk / 3 - 1) * 78 + (kk % 3 - 1)) * 512 + (t & 7) * 64;
#pragma unroll
        for (int h = 0; h < 2; ++h)
#pragma unroll
            for (int j = 0; j < 2; ++j)
                __builtin_amdgcn_global_load_lds(GPTR(P + cbA[h][j] + tap),
                    LDSPTR(abase + h * 16384 + j * 8192 + w * 1024), 16, 0, 0);
    };
    auto stB = [&](int t, unsigned char* bbase) {
#pragma unroll
        for (int h = 0; h < 2; ++h)
#pragma unroll
            for (int j = 0; j < 2; ++j)
                __builtin_amdgcn_global_load_lds(GPTR(Wt + nbB[h][j] + t * 64),
                    LDSPTR(bbase + h * 16384 + j * 8192 + w * 1024), 16, 0, 0);
    };

    f32x4 acc[8][4];
#pragma unroll
    for (int i = 0; i < 8; ++i)
#pragma unroll
        for (int j = 0; j < 4; ++j) acc[i][j] = (f32x4){0.f, 0.f, 0.f, 0.f};

#define RD(basep, subR, ks) (*(const bf16x8*)((basep) + (((subR) * 2 + (ks)) * 1024) + loff))
#define ABUF(t) (lds + ((t) % 3) * 32768)
#define BBUF(t) (lds + 98304 + ((t) & 1) * 32768)

    // ---- prologue: issue B0 (oldest), A0, A1; counted retire of tile 0 ----
    stB(0, BBUF(0));
    stA(0, ABUF(0));
    stA(1, ABUF(1));
    SB();
    asm volatile("s_waitcnt vmcnt(4)" ::: "memory");   // retire B0+A0 (8 oldest)
    __builtin_amdgcn_s_barrier();
    SB();

    for (int g = 0; g < NT; ++g) {
        unsigned char* Ah = ABUF(g) + wr * 16384;   // this wave's A half
        unsigned char* Bh = BBUF(g) + hB * 16384;   // this wave's B half

        // issue next staging: B(g+1) FIRST (older in FIFO), then A(g+2)
        if (g + 1 < NT) stB(g + 1, BBUF(g + 1));
        if (g + 2 < NT) stA(g + 2, ABUF(g + 2));
        SB();

        // k-half-major: two passes of {12 reads, 32 MFMA} (r15 verbatim)
#pragma unroll
        for (int ks = 0; ks < 2; ++ks) {
            bf16x8 a[8], b[4];
#pragma unroll
            for (int f = 0; f < 8; ++f) a[f] = RD(Ah, f, ks);
#pragma unroll
            for (int n = 0; n < 4; ++n) b[n] = RD(Bh, rB + n, ks);
#pragma unroll
            for (int n = 0; n < 4; ++n)
#pragma unroll
                for (int f = 0; f < 8; ++f)
                    acc[f][n] = MFMA16(a[f], b[n], acc[f][n], 0, 0, 0);
        }

        // counted publish: retire A(g+1)+B(g+1); keep A(g+2) in flight
        SB();
        if (g + 2 < NT)       asm volatile("s_waitcnt vmcnt(4)" ::: "memory");
        else if (g + 1 < NT)  asm volatile("s_waitcnt vmcnt(0)" ::: "memory");
        __builtin_amdgcn_s_barrier();
        SB();
    }
#undef ABUF
#undef BBUF
#undef RD

    // ---- epilogue: bias + relu + bf16 store ----
#pragma unroll
    for (int ni = 0; ni < 4; ++ni) {
        const int col = n0 + nc * 64 + ni * 16 + (l & 15);
        const float bcol = bias[col];
#pragma unroll
        for (int mi = 0; mi < 8; ++mi) {
#pragma unroll
            for (int jj = 0; jj < 4; ++jj) {
                const int row = m0 + wr * 128 + mi * 16 + (l >> 4) * 4 + jj;
                if (row < MTOT)
                    F[row * 512 + col] = f2bf(fmaxf(acc[mi][ni][jj] + bcol, 0.f));
            }
        }
    }
}

// ---------------- 5) head GEMM (N=54 in 64) + anchor decode ----------------
__global__ __launch_bounds__(256) void head_decode(
    const unsigned short* __restrict__ F,
    const unsigned short* __restrict__ W2,
    const float* __restrict__ b2,
    const int* __restrict__ img,
    float* __restrict__ out)
{
    __shared__ float S[64][56];
    const int tid  = threadIdx.x;
    const int lane = tid & 63;
    const int wv   = tid >> 6;
    const int mblk = blockIdx.x * 64;
    int arow = mblk + wv * 16 + (lane & 15);
    if (arow >= MTOT) arow = MTOT - 1;   // clamp: tail S rows computed but never decoded

    f32x4 acc[4];
#pragma unroll
    for (int ni = 0; ni < 4; ++ni) acc[ni] = (f32x4){0.f, 0.f, 0.f, 0.f};

#pragma unroll 4
    for (int ks = 0; ks < 16; ++ks) {
        const int kloc = ks * 32 + (lane >> 4) * 8;
        bf16x8 a = *(const bf16x8*)(F + arow * 512 + kloc);
#pragma unroll
        for (int ni = 0; ni < 4; ++ni) {
            bf16x8 b = *(const bf16x8*)(W2 + (ni * 16 + (lane & 15)) * 512 + kloc);
            acc[ni] = MFMA16(a, b, acc[ni], 0, 0, 0);
        }
    }

#pragma unroll
    for (int ni = 0; ni < 4; ++ni) {
        int col = ni * 16 + (lane & 15);
        if (col < 54) {
            float bb = b2[col];
#pragma unroll
            for (int j = 0; j < 4; ++j)
                S[wv * 16 + (lane >> 4) * 4 + j][col] = acc[ni][j] + bb;
        }
    }
    __syncthreads();

    for (int it = tid; it < 576; it += 256) {
        int rowl = it / 9;
        int a    = it - rowl * 9;
        int m = mblk + rowl;
        if (m >= MTOT) continue;
        int b   = m / 3800;
        int rem = m - b * 3800;
        int y = rem / 76;
        int x = rem - y * 76;

        int ri = a / 3, si = a - ri * 3;
        float sqr = (ri == 0) ? 0.70710678118654752f : ((ri == 1) ? 1.f : 1.41421356237309515f);
        float scale = (float)(128 << si);
        float wa = scale / sqr;
        float ha = scale * sqr;
        float ax = (float)x * 16.f + 8.f;
        float ay = (float)y * 16.f + 8.f;

        float r0 = S[rowl][18 + a * 4 + 0];
        float r1 = S[rowl][18 + a * 4 + 1];
        float r2 = S[rowl][18 + a * 4 + 2];
        float r3 = S[rowl][18 + a * 4 + 3];

        float px = ax + r0 * wa;
        float py = ay + r1 * ha;
        float pw = wa * expf(r2);
        float ph = ha * expf(r3);

        float x1 = px - 0.5f * pw, y1 = py - 0.5f * ph;
        float x2 = x1 + pw,        y2 = y1 + ph;
        float imx = (float)img[2 * b], imy = (float)img[2 * b + 1];
        x1 = fminf(fmaxf(x1, 0.f), imx); x2 = fminf(fmaxf(x2, 0.f), imx);
        y1 = fminf(fmaxf(y1, 0.f), imy); y2 = fminf(fmaxf(y2, 0.f), imy);
        float ww = x2 - x1, hh = y2 - y1;
        float cx = x1 + 0.5f * ww, cy = y1 + 0.5f * hh;

        int pidx = b * 34200 + rem * 9 + a;
        ((float4*)out)[pidx] = make_float4(cx, cy, ww, hh);
        float* oc = out + 1094400 + pidx * 2;
        oc[0] = S[rowl][a * 2 + 0];
        oc[1] = S[rowl][a * 2 + 1];
    }
}

// ---------------- launcher ----------------
extern "C" void kernel_launch(void* const* d_in, const int* in_sizes, int n_in,
                              void* d_out, int out_size, void* d_ws, size_t ws_size,
                              hipStream_t stream) {
    const float* fm     = (const float*)d_in[0];
    const float* conv_w = (const float*)d_in[1];
    const float* conv_b = (const float*)d_in[2];
    const float* cls_w  = (const float*)d_in[3];
    const float* cls_b  = (const float*)d_in[4];
    const float* reg_w  = (const float*)d_in[5];
    const float* reg_b  = (const float*)d_in[6];
    const int*   img    = (const int*)d_in[7];
    float* out = (float*)d_out;

    char* ws = (char*)d_ws;
    unsigned short* P  = (unsigned short*)(ws);
    unsigned short* Wt = (unsigned short*)(ws + 33226752);
    unsigned short* F  = (unsigned short*)(ws + 37945344);
    unsigned short* W2 = (unsigned short*)(ws + 69140480);
    float*          b2 = (float*)(ws + 69206016);

    // prep_all: Wt (9216) + head weights (128) + P border zero (512) + pad_transpose (9600)
    prep_all<<<19456, 256, 0, stream>>>(conv_w, cls_w, reg_w, cls_b, reg_b, fm,
                                        Wt, W2, b2, P);
    conv_gemm8<<<dim3(119, 2), 512, 0, stream>>>(P, Wt, conv_b, F);
    head_decode<<<475, 256, 0, stream>>>(F, W2, b2, img, out);
}

// Round 18
// 189.389 us; speedup vs baseline: 1.4626x; 1.0165x over previous
//
#include <hip/hip_runtime.h>

// ---------------- types / helpers ----------------
typedef __attribute__((ext_vector_type(8))) __bf16 bf16x8;
typedef __attribute__((ext_vector_type(4))) float  f32x4;

#define GPTR(p)   (__attribute__((address_space(1))) void*)(p)
#define LDSPTR(p) (__attribute__((address_space(3))) void*)(p)
#define MFMA16 __builtin_amdgcn_mfma_f32_16x16x32_bf16
#define SB() __builtin_amdgcn_sched_barrier(0)

__device__ __forceinline__ unsigned short f2bf(float f) {
    union { float f; unsigned u; } v; v.f = f;
    unsigned r = v.u + 0x7FFF + ((v.u >> 16) & 1);   // RNE
    return (unsigned short)(r >> 16);
}

// Problem constants
#define MTOT   30400
#define MPAD   30464
#define KTOT   4608
#define NT     72          // K tiles of 64

// ---------------- 1) fused prep_all: Wt (B^T), head W2/b2, P border zero, pad_transpose ----
__global__ __launch_bounds__(256) void prep_all(
    const float* __restrict__ cw,
    const float* __restrict__ cls_w, const float* __restrict__ reg_w,
    const float* __restrict__ cls_b, const float* __restrict__ reg_b,
    const float* __restrict__ fm,
    unsigned short* __restrict__ Wt,
    unsigned short* __restrict__ W2, float* __restrict__ b2,
    unsigned short* __restrict__ P)
{
    __shared__ float t[32][65];
    int bid = blockIdx.x;
    if (bid < 9216) {                               // Wt
        int i = bid * 256 + threadIdx.x;            // < 512*4608
        int o = i / KTOT;
        int r = i - o * KTOT;
        int kk = r >> 9;
        int c  = r & 511;
        Wt[i] = f2bf(cw[(o * 512 + c) * 9 + kk]);
    } else if (bid < 9344) {                        // W2[64][512], b2[64]
        int i = (bid - 9216) * 256 + threadIdx.x;   // < 64*512
        int n = i >> 9, k = i & 511;
        float v = 0.f;
        if (n < 18) v = cls_w[n * 512 + k];
        else if (n < 54) v = reg_w[(n - 18) * 512 + k];
        W2[i] = f2bf(v);
        if (i < 64) {
            float bv = 0.f;
            if (i < 18) bv = cls_b[i];
            else if (i < 54) bv = reg_b[i - 18];
            b2[i] = bv;
        }
    } else if (bid < 9856) {                        // P pad-border zero
        int i = (bid - 9344) * 256 + threadIdx.x;   // < 8*256*64 = 131072
        int b   = i >> 14;
        int rem = i & 16383;
        int seg = rem >> 6;                         // 0..255
        int c8  = (rem & 63) << 3;
        int y, x;
        if (seg < 78)       { y = 0;  x = seg; }
        else if (seg < 156) { y = 51; x = seg - 78; }
        else if (seg < 206) { y = seg - 155; x = 0; }
        else                { y = seg - 205; x = 77; }
        *(float4*)(P + ((b * 52 + y) * 78 + x) * 512 + c8) = make_float4(0.f, 0.f, 0.f, 0.f);
    } else {                                        // pad_transpose interior
        int bid2 = bid - 9856;                      // < 24*50*8 = 9600
        const int tid = threadIdx.x;
        const int tx  = tid & 31;                   // x within tile (read side)
        const int ty  = tid >> 5;                   // 0..7
        const int xp  = bid2 % 24;
        const int tix = xp % 3;                     // x tile (0..2)
        const int cix = xp / 3;                     // c tile (0..7)
        const int y   = (bid2 / 24) % 50;
        const int b   = bid2 / 1200;
        const int x0  = tix * 32, c0 = cix * 64;

        const int x = x0 + tx;
        if (x < 76) {
#pragma unroll
            for (int i = 0; i < 8; ++i) {
                int cc = i * 8 + ty;                // 0..63
                t[tx][cc] = fm[((b * 512 + c0 + cc) * 50 + y) * 76 + x];
            }
        }
        __syncthreads();

        const int p = tid >> 6;                     // pixel group 0..3
        const int c = tid & 63;                     // channel lane
#pragma unroll
        for (int xi = 0; xi < 8; ++xi) {
            int xr = p * 8 + xi;                    // 0..31
            int xw = x0 + xr;
            if (xw < 76)
                P[((b * 52 + y + 1) * 78 + (xw + 1)) * 512 + c0 + c] = f2bf(t[xr][c]);
        }
    }
}

// ---------------- 4) conv implicit GEMM (r15 configuration: best measured, 143.5 us) ----------
// 256x256, BK=64, 8 waves (2M x 4N), k-half-major body, 1 sync/tile double
// buffer (A+B in LDS, 128KB), st_16x32 swizzle via pre-swizzled global source,
// XCD-chunked grid. Converged plateau: per-tile = LDS reads 2300 cyc (192 x
// b128, conflict-free, 3x inter-wave read amplification — invariant under
// wave layout within LDS/reg budgets) + staging ~500 + MFMA 620, at ~60%
// LDS-pipe utilization. 10 schedule variants (lockstep 8-phase, balanced,
// barrier-free, k-half, reg-pipeline, TLP 4-block, B-direct, counted-vmcnt
// 3-buf) all land 39-43% MfmaUtil; this one is the measured best.
__global__ __launch_bounds__(512, 2) void conv_gemm8(
    const unsigned short* __restrict__ P,    // padded NHWC bf16
    const unsigned short* __restrict__ Wt,   // [512][4608] bf16
    const float* __restrict__ bias,
    unsigned short* __restrict__ F)          // [MPAD][512] bf16
{
    __shared__ __attribute__((aligned(1024))) unsigned char lds[131072];

    const int tid = threadIdx.x;
    const int l   = tid & 63;
    const int w   = tid >> 6;          // wave 0..7
    const int wr  = w >> 2;            // M group 0..1 (owns 128 rows = one A half)
    const int nc  = w & 3;             // N group 0..3 (owns 64 cols)
    const int hB  = nc >> 1;           // which B half this wave reads
    const int rB  = (nc & 1) * 4;      // subtile-R base within the B half

    // bijective XCD-chunked block swizzle (nwg=238=8*29+6, m204 formula)
    const int orig = blockIdx.y * 119 + blockIdx.x;
    const int xcd = orig & 7, seq = orig >> 3;
    const int wg  = (xcd < 6 ? xcd * 30 : 180 + (xcd - 6) * 29) + seq;
    const int m0  = (wg % 119) * 256;
    const int n0  = (wg / 119) * 256;

    // swizzled read lane offset within a 1024B subtile
    const int loff = (l & 15) * 64 + (((l >> 4) * 16) ^ ((l & 8) ? 32 : 0));
    // swizzled stage source k-element offset (inverse of read swizzle)
    const int kelS = ((l & 3) * 8) ^ ((l & 32) ? 16 : 0);

    // Per-thread global base offsets for staging (half h, load j).
    int cbA[2][2], nbB[2][2];
#pragma unroll
    for (int h = 0; h < 2; ++h)
#pragma unroll
        for (int j = 0; j < 2; ++j) {
            const int s    = j * 8 + w;                          // subtile 0..15
            const int rowt = h * 128 + (s >> 1) * 16 + (l >> 2); // row in 256-tile
            int m = m0 + rowt; if (m >= MTOT) m = 0;             // clamp (stores guarded)
            int b = m / 3800; int r = m - b * 3800;
            int y = r / 76;   int x = r - y * 76;
            cbA[h][j] = ((b * 52 + y + 1) * 78 + (x + 1)) * 512 + (s & 1) * 32 + kelS;
            nbB[h][j] = (n0 + rowt) * KTOT + (s & 1) * 32 + kelS;
        }

    auto stA = [&](int t, int h, unsigned char* abase) {
        const int kk  = t >> 3;
        const int tap = ((kk / 3 - 1) * 78 + (kk % 3 - 1)) * 512 + (t & 7) * 64;
#pragma unroll
        for (int j = 0; j < 2; ++j)
            __builtin_amdgcn_global_load_lds(GPTR(P + cbA[h][j] + tap),
                LDSPTR(abase + h * 16384 + j * 8192 + w * 1024), 16, 0, 0);
    };
    auto stB = [&](int t, int h, unsigned char* bbase) {
#pragma unroll
        for (int j = 0; j < 2; ++j)
            __builtin_amdgcn_global_load_lds(GPTR(Wt + nbB[h][j] + t * 64),
                LDSPTR(bbase + h * 16384 + j * 8192 + w * 1024), 16, 0, 0);
    };

    f32x4 acc[8][4];
#pragma unroll
    for (int i = 0; i < 8; ++i)
#pragma unroll
        for (int j = 0; j < 4; ++j) acc[i][j] = (f32x4){0.f, 0.f, 0.f, 0.f};

#define RD(basep, subR, ks) (*(const bf16x8*)((basep) + (((subR) * 2 + (ks)) * 1024) + loff))

    // ---- prologue: stage tile 0 into buf0; single sync (implicit vmcnt(0)) ----
    {
        unsigned char* A0b = lds;
        unsigned char* B0b = lds + 32768;
        stB(0, 0, B0b); stB(0, 1, B0b); stA(0, 0, A0b); stA(0, 1, A0b);
        __syncthreads();
    }

    for (int g = 0; g < NT; ++g) {
        unsigned char* Ac = lds + (g & 1) * 65536;
        unsigned char* Bc = Ac + 32768;
        unsigned char* An = lds + (((g & 1) ^ 1)) * 65536;
        unsigned char* Bn = An + 32768;
        unsigned char* Ah = Ac + wr * 16384;   // this wave's A half
        unsigned char* Bh = Bc + hB * 16384;   // this wave's B half

        // stage tile g+1 into the idle buffer (full-tile latency cover)
        if (g + 1 < NT) {
            stB(g + 1, 0, Bn); stB(g + 1, 1, Bn);
            stA(g + 1, 0, An); stA(g + 1, 1, An);
        }
        SB();

        // k-half-major: two passes of {12 reads, 32 MFMA}; 48 operand VGPRs live
#pragma unroll
        for (int ks = 0; ks < 2; ++ks) {
            bf16x8 a[8], b[4];
#pragma unroll
            for (int f = 0; f < 8; ++f) a[f] = RD(Ah, f, ks);
#pragma unroll
            for (int n = 0; n < 4; ++n) b[n] = RD(Bh, rB + n, ks);
#pragma unroll
            for (int n = 0; n < 4; ++n)
#pragma unroll
                for (int f = 0; f < 8; ++f)
                    acc[f][n] = MFMA16(a[f], b[n], acc[f][n], 0, 0, 0);
        }

        // single per-tile sync: implicit vmcnt(0) retires the top-staged loads
        __syncthreads();
    }
#undef RD

    // ---- epilogue: bias + relu + bf16 store ----
#pragma unroll
    for (int ni = 0; ni < 4; ++ni) {
        const int col = n0 + nc * 64 + ni * 16 + (l & 15);
        const float bcol = bias[col];
#pragma unroll
        for (int mi = 0; mi < 8; ++mi) {
#pragma unroll
            for (int jj = 0; jj < 4; ++jj) {
                const int row = m0 + wr * 128 + mi * 16 + (l >> 4) * 4 + jj;
                if (row < MTOT)
                    F[row * 512 + col] = f2bf(fmaxf(acc[mi][ni][jj] + bcol, 0.f));
            }
        }
    }
}

// ---------------- 5) head GEMM (N=54 in 64) + anchor decode ----------------
__global__ __launch_bounds__(256) void head_decode(
    const unsigned short* __restrict__ F,
    const unsigned short* __restrict__ W2,
    const float* __restrict__ b2,
    const int* __restrict__ img,
    float* __restrict__ out)
{
    __shared__ float S[64][56];
    const int tid  = threadIdx.x;
    const int lane = tid & 63;
    const int wv   = tid >> 6;
    const int mblk = blockIdx.x * 64;
    int arow = mblk + wv * 16 + (lane & 15);
    if (arow >= MTOT) arow = MTOT - 1;   // clamp: tail S rows computed but never decoded

    f32x4 acc[4];
#pragma unroll
    for (int ni = 0; ni < 4; ++ni) acc[ni] = (f32x4){0.f, 0.f, 0.f, 0.f};

#pragma unroll 4
    for (int ks = 0; ks < 16; ++ks) {
        const int kloc = ks * 32 + (lane >> 4) * 8;
        bf16x8 a = *(const bf16x8*)(F + arow * 512 + kloc);
#pragma unroll
        for (int ni = 0; ni < 4; ++ni) {
            bf16x8 b = *(const bf16x8*)(W2 + (ni * 16 + (lane & 15)) * 512 + kloc);
            acc[ni] = MFMA16(a, b, acc[ni], 0, 0, 0);
        }
    }

#pragma unroll
    for (int ni = 0; ni < 4; ++ni) {
        int col = ni * 16 + (lane & 15);
        if (col < 54) {
            float bb = b2[col];
#pragma unroll
            for (int j = 0; j < 4; ++j)
                S[wv * 16 + (lane >> 4) * 4 + j][col] = acc[ni][j] + bb;
        }
    }
    __syncthreads();

    for (int it = tid; it < 576; it += 256) {
        int rowl = it / 9;
        int a    = it - rowl * 9;
        int m = mblk + rowl;
        if (m >= MTOT) continue;
        int b   = m / 3800;
        int rem = m - b * 3800;
        int y = rem / 76;
        int x = rem - y * 76;

        int ri = a / 3, si = a - ri * 3;
        float sqr = (ri == 0) ? 0.70710678118654752f : ((ri == 1) ? 1.f : 1.41421356237309515f);
        float scale = (float)(128 << si);
        float wa = scale / sqr;
        float ha = scale * sqr;
        float ax = (float)x * 16.f + 8.f;
        float ay = (float)y * 16.f + 8.f;

        float r0 = S[rowl][18 + a * 4 + 0];
        float r1 = S[rowl][18 + a * 4 + 1];
        float r2 = S[rowl][18 + a * 4 + 2];
        float r3 = S[rowl][18 + a * 4 + 3];

        float px = ax + r0 * wa;
        float py = ay + r1 * ha;
        float pw = wa * expf(r2);
        float ph = ha * expf(r3);

        float x1 = px - 0.5f * pw, y1 = py - 0.5f * ph;
        float x2 = x1 + pw,        y2 = y1 + ph;
        float imx = (float)img[2 * b], imy = (float)img[2 * b + 1];
        x1 = fminf(fmaxf(x1, 0.f), imx); x2 = fminf(fmaxf(x2, 0.f), imx);
        y1 = fminf(fmaxf(y1, 0.f), imy); y2 = fminf(fmaxf(y2, 0.f), imy);
        float ww = x2 - x1, hh = y2 - y1;
        float cx = x1 + 0.5f * ww, cy = y1 + 0.5f * hh;

        int pidx = b * 34200 + rem * 9 + a;
        ((float4*)out)[pidx] = make_float4(cx, cy, ww, hh);
        float* oc = out + 1094400 + pidx * 2;
        oc[0] = S[rowl][a * 2 + 0];
        oc[1] = S[rowl][a * 2 + 1];
    }
}

// ---------------- launcher ----------------
extern "C" void kernel_launch(void* const* d_in, const int* in_sizes, int n_in,
                              void* d_out, int out_size, void* d_ws, size_t ws_size,
                              hipStream_t stream) {
    const float* fm     = (const float*)d_in[0];
    const float* conv_w = (const float*)d_in[1];
    const float* conv_b = (const float*)d_in[2];
    const float* cls_w  = (const float*)d_in[3];
    const float* cls_b  = (const float*)d_in[4];
    const float* reg_w  = (const float*)d_in[5];
    const float* reg_b  = (const float*)d_in[6];
    const int*   img    = (const int*)d_in[7];
    float* out = (float*)d_out;

    char* ws = (char*)d_ws;
    unsigned short* P  = (unsigned short*)(ws);
    unsigned short* Wt = (unsigned short*)(ws + 33226752);
    unsigned short* F  = (unsigned short*)(ws + 37945344);
    unsigned short* W2 = (unsigned short*)(ws + 69140480);
    float*          b2 = (float*)(ws + 69206016);

    // prep_all: Wt (9216) + head weights (128) + P border zero (512) + pad_transpose (9600)
    prep_all<<<19456, 256, 0, stream>>>(conv_w, cls_w, reg_w, cls_b, reg_b, fm,
                                        Wt, W2, b2, P);
    conv_gemm8<<<dim3(119, 2), 512, 0, stream>>>(P, Wt, conv_b, F);
    head_decode<<<475, 256, 0, stream>>>(F, W2, b2, img, out);
}